// Round 7
// baseline (681.227 us; speedup 1.0000x reference)
//
#include <hip/hip_runtime.h>
#include <math.h>

#define WAYS 32
#define NTOT 2048
#define XD 84
#define FLAT 3610
#define KSPLIT 16
#define KCHUNK 226  // ceil(3610/16)

__device__ __forceinline__ float softplus_f(float x) {
    return (x > 20.f) ? x : log1pf(expf(x));
}
__device__ __forceinline__ float kl_f(float mu, float sd) {
    return -logf(sd) + 0.5f * (sd * sd + mu * mu) - 0.5f;
}

// ---------------------------------------------------------------------------
// Fused conv1+relu+pool -> conv2+relu+pool.
// v5: v4 structure (10 bands of 2 p2 rows, LDS 30.8KB) but launch_bounds
// (256,4): the conv1 body needs ~84 VGPRs (R2 measurement); (256,5)'s
// ~102-reg cap made the allocator collapse to 48 and spill acc[10][4]
// (R6: WRITE_SIZE 83.6MB vs 29.6MB of real output). Cap 128 regs; actual
// occupancy = min(LDS 5 blocks, VGPR 512/84=6) = 5 blocks/CU, spill-free.
// ---------------------------------------------------------------------------
__global__ __launch_bounds__(256, 4) void k_conv(
        const float* __restrict__ x,
        const float* __restrict__ w1, const float* __restrict__ b1,
        const float* __restrict__ w2, const float* __restrict__ b2,
        float* __restrict__ p2) {
    __shared__ __align__(16) float xs[3 * 14 * 84];  // [c][row][col] 14112 B
    __shared__ __align__(16) float p1s[10 * 6 * 40]; // [ic][q][col]   9600 B
    __shared__ __align__(16) float w1t[27 * 12];     // [c*9+k][oc(10) pad 12]
    __shared__ __align__(16) float w2t[90 * 16];     // [ic*9+k][h*8+o pad 16]

    const int tid  = threadIdx.x;
    const int img  = blockIdx.x & 2047;
    const int band = blockIdx.x >> 11;       // 0..9
    const int r0   = band * 2;               // first p2 row
    const int nr   = (band < 9) ? 2 : 1;     // p2 rows in band
    const int nq   = 2 * nr + 2;             // p1 rows needed (6 or 4)
    const int xr0  = 8 * band;               // first x row
    const int nxr  = 2 * nq + 2;             // x rows (14 or 10)

    // ---- stage x band (float4 copies; both sides 16B aligned) ----
    {
        const float* xg = x + (size_t)img * (3 * XD * XD);
        const int nv = (nxr * 84) >> 2;      // 294 or 210 float4s
        #pragma unroll
        for (int c = 0; c < 3; c++) {
            const float4* src = (const float4*)(xg + c * (XD * XD) + xr0 * 84);
            float4* dst = (float4*)(xs + c * (14 * 84));
            for (int i = tid; i < nv; i += 256) dst[i] = src[i];
        }
    }
    // ---- stage weights transposed (oc innermost) ----
    for (int i = tid; i < 270; i += 256) {
        int oc = i / 27, r = i - oc * 27;    // r = c*9 + ky*3 + kx
        w1t[r * 12 + oc] = w1[i];
    }
    for (int i = tid; i < 900; i += 256) {
        int oc = i / 90, r = i - oc * 90;    // r = ic*9 + ky*3 + kx
        int h = oc / 5, o = oc - h * 5;
        w2t[r * 16 + h * 8 + o] = w2[i];
    }
    float b1r[10];
    #pragma unroll
    for (int o = 0; o < 10; o++) b1r[o] = b1[o];
    __syncthreads();

    // ---- conv1 + relu + pool -> p1s (all 10 oc per item, single pass) ----
    {
        const int n1 = nq * 40;              // 240 or 160
        if (tid < n1) {
            int q = tid / 40;                // local p1 row
            int p = tid - q * 40;            // p1 col
            float acc[10][4];
            #pragma unroll
            for (int o = 0; o < 10; o++)
                #pragma unroll
                for (int j = 0; j < 4; j++) acc[o][j] = 0.f;
            #pragma unroll 1
            for (int c = 0; c < 3; c++) {
                float xp[4][4];
                #pragma unroll
                for (int rr = 0; rr < 4; rr++) {
                    const float2* row =
                        (const float2*)&xs[c * (14 * 84) + (2 * q + rr) * 84 + 2 * p];
                    float2 lo = row[0], hi = row[1];
                    xp[rr][0] = lo.x; xp[rr][1] = lo.y;
                    xp[rr][2] = hi.x; xp[rr][3] = hi.y;
                }
                #pragma unroll
                for (int ky = 0; ky < 3; ky++) {
                    #pragma unroll
                    for (int kx = 0; kx < 3; kx++) {
                        const float* wr = &w1t[(c * 9 + ky * 3 + kx) * 12];
                        float4 wA = *(const float4*)(wr);
                        float4 wB = *(const float4*)(wr + 4);
                        float2 wC = *(const float2*)(wr + 8);
                        float wv[10] = {wA.x, wA.y, wA.z, wA.w,
                                        wB.x, wB.y, wB.z, wB.w,
                                        wC.x, wC.y};
                        #pragma unroll
                        for (int o = 0; o < 10; o++) {
                            float w = wv[o];
                            acc[o][0] = fmaf(xp[ky][kx],         w, acc[o][0]);
                            acc[o][1] = fmaf(xp[ky][kx + 1],     w, acc[o][1]);
                            acc[o][2] = fmaf(xp[ky + 1][kx],     w, acc[o][2]);
                            acc[o][3] = fmaf(xp[ky + 1][kx + 1], w, acc[o][3]);
                        }
                    }
                }
            }
            #pragma unroll
            for (int o = 0; o < 10; o++) {
                float m = fmaxf(fmaxf(acc[o][0], acc[o][1]), fmaxf(acc[o][2], acc[o][3]));
                p1s[o * 240 + q * 40 + p] = fmaxf(m + b1r[o], 0.f);
            }
        }
    }
    __syncthreads();

    // ---- conv2 + relu + pool -> p2 (global) ----
    {
        const int npos = nr * 19;            // 38 or 19
        if (tid < 2 * npos) {
            int half = (tid >= npos) ? 1 : 0;
            int pos  = tid - npos * half;
            int pr = pos / 19;               // local p2 row
            int pc = pos - pr * 19;
            float acc[5][4];
            #pragma unroll
            for (int o = 0; o < 5; o++)
                #pragma unroll
                for (int j = 0; j < 4; j++) acc[o][j] = 0.f;
            #pragma unroll 1
            for (int ic = 0; ic < 10; ic++) {
                float xp[4][4];
                #pragma unroll
                for (int rr = 0; rr < 4; rr++) {
                    const float2* row =
                        (const float2*)&p1s[ic * 240 + (2 * pr + rr) * 40 + 2 * pc];
                    float2 lo = row[0], hi = row[1];
                    xp[rr][0] = lo.x; xp[rr][1] = lo.y;
                    xp[rr][2] = hi.x; xp[rr][3] = hi.y;
                }
                #pragma unroll
                for (int ky = 0; ky < 3; ky++) {
                    #pragma unroll
                    for (int kx = 0; kx < 3; kx++) {
                        const float* wr = &w2t[(ic * 9 + ky * 3 + kx) * 16 + half * 8];
                        float4 wA = *(const float4*)(wr);
                        float w4 = wr[4];
                        float wv[5] = {wA.x, wA.y, wA.z, wA.w, w4};
                        #pragma unroll
                        for (int o = 0; o < 5; o++) {
                            float w = wv[o];
                            acc[o][0] = fmaf(xp[ky][kx],         w, acc[o][0]);
                            acc[o][1] = fmaf(xp[ky][kx + 1],     w, acc[o][1]);
                            acc[o][2] = fmaf(xp[ky + 1][kx],     w, acc[o][2]);
                            acc[o][3] = fmaf(xp[ky + 1][kx + 1], w, acc[o][3]);
                        }
                    }
                }
            }
            float* outp = p2 + (size_t)img * FLAT;
            #pragma unroll
            for (int o = 0; o < 5; o++) {
                int oc = half * 5 + o;
                float m = fmaxf(fmaxf(acc[o][0], acc[o][1]), fmaxf(acc[o][2], acc[o][3]));
                outp[oc * 361 + (r0 + pr) * 19 + pc] = fmaxf(m + b2[oc], 0.f);
            }
        }
    }
}

// ---------------------------------------------------------------------------
__global__ void k_label(const float* __restrict__ y, int* __restrict__ label) {
    int n = blockIdx.x * 256 + threadIdx.x;
    if (n >= NTOT) return;
    const float* yr = y + n * WAYS;
    float best = yr[0]; int bi = 0;
    for (int k = 1; k < WAYS; k++) {
        float v = yr[k];
        if (v > best) { best = v; bi = k; }
    }
    label[n] = bi;
}

// ---------------------------------------------------------------------------
// enc GEMM: H[2048,64] += p2[2048,3610] @ enc_w[3610,64]  (split-K, atomics)
// a_s stride 68 (16B-aligned rows) -> both operands load as float4.
// ---------------------------------------------------------------------------
__global__ __launch_bounds__(256, 2) void k_enc(
        const float* __restrict__ A, const float* __restrict__ W,
        float* __restrict__ H) {
    __shared__ __align__(16) float a_s[32 * 68];
    __shared__ __align__(16) float w_s[32 * 64];
    int mb = blockIdx.x >> 4;
    int ks = blockIdx.x & 15;
    int row0 = mb * 64;
    int kbeg = ks * KCHUNK;
    int kend = min(kbeg + KCHUNK, FLAT);
    int tid = threadIdx.x;
    int tr = tid & 15, tc = tid >> 4;
    float acc[4][4] = {};

    for (int k0 = kbeg; k0 < kend; k0 += 32) {
        {
            int kk = tid & 31;
            int r  = tid >> 5;
            int gk = k0 + kk;
            #pragma unroll
            for (int i = 0; i < 8; i++) {
                int rr = r + i * 8;
                float v = (gk < kend) ? A[(size_t)(row0 + rr) * FLAT + gk] : 0.f;
                a_s[kk * 68 + rr] = v;
            }
            int c  = tid & 63;
            int kw = tid >> 6;
            #pragma unroll
            for (int i = 0; i < 8; i++) {
                int kk2 = kw + i * 4;
                int gk2 = k0 + kk2;
                float v = (gk2 < kend) ? W[(size_t)gk2 * 64 + c] : 0.f;
                w_s[kk2 * 64 + c] = v;
            }
        }
        __syncthreads();
        #pragma unroll 8
        for (int k = 0; k < 32; k++) {
            float4 av4 = *(const float4*)&a_s[k * 68 + tr * 4];
            float4 wv4 = *(const float4*)&w_s[k * 64 + tc * 4];
            float av[4] = {av4.x, av4.y, av4.z, av4.w};
            float wv[4] = {wv4.x, wv4.y, wv4.z, wv4.w};
            #pragma unroll
            for (int i = 0; i < 4; i++)
                #pragma unroll
                for (int j = 0; j < 4; j++)
                    acc[i][j] = fmaf(av[i], wv[j], acc[i][j]);
        }
        __syncthreads();
    }
    #pragma unroll
    for (int i = 0; i < 4; i++)
        #pragma unroll
        for (int j = 0; j < 4; j++)
            atomicAdd(&H[(size_t)(row0 + tr * 4 + i) * 64 + tc * 4 + j], acc[i][j]);
}

// ---------------------------------------------------------------------------
// labels staged in LDS, branchless masked accumulation, 1024 threads.
// ---------------------------------------------------------------------------
__global__ __launch_bounds__(1024) void k_stats(
        const float* __restrict__ H, const float* __restrict__ encb,
        const int* __restrict__ label,
        const float* __restrict__ t1w, const float* __restrict__ t1b,
        float* __restrict__ cs, float* __restrict__ card) {
    __shared__ int   lbl_s[NTOT];
    __shared__ float rs[16][64], rs2[16][64];
    __shared__ int rc[16];
    int w = blockIdx.x;
    int tid = threadIdx.x;
    for (int i = tid; i < NTOT; i += 1024) lbl_s[i] = label[i];
    __syncthreads();
    int c = tid & 63, g = tid >> 6;          // g in 0..15
    float eb = encb[c];
    float s = 0.f, s2 = 0.f; int cnt = 0;
    #pragma unroll 4
    for (int n = g; n < NTOT; n += 16) {
        bool m = (lbl_s[n] == w);
        float hv = H[n * 64 + c] + eb;
        float hm = m ? hv : 0.f;
        s += hm; s2 += hm * hm; cnt += m ? 1 : 0;
    }
    rs[g][c] = s; rs2[g][c] = s2;
    if (c == 0) rc[g] = cnt;
    __syncthreads();
    if (g == 0) {
        float S = 0.f, S2 = 0.f; int CNT = 0;
        #pragma unroll
        for (int gg = 0; gg < 16; gg++) {
            S += rs[gg][c]; S2 += rs2[gg][c]; CNT += rc[gg];
        }
        float mean = S / 2048.f;
        float var  = (S2 - S * S / 2048.f) / 2047.f;
        float cd   = ((float)CNT - 1.f) / 63.f;
        #pragma unroll
        for (int j = 0; j < 4; j++)
            cs[w * 256 + c * 4 + j] =
                fmaxf(mean * t1w[j] + var * t1w[4 + j] + cd * t1w[8 + j] + t1b[j], 0.f);
        if (c == 0) card[w] = cd;
    }
}

// ---------------------------------------------------------------------------
// omega spread over 256 threads (8-way k-split), gamma/zeta input layer
// spread over 256 threads (4-way k-split), vectorized GEMM operand loads.
// ---------------------------------------------------------------------------
__global__ __launch_bounds__(256) void k_head(
        const float* __restrict__ cs_g, const float* __restrict__ card,
        const float* __restrict__ te2w1, const float* __restrict__ te2b1,
        const float* __restrict__ te2w2, const float* __restrict__ te2b2,
        const float* __restrict__ t2w, const float* __restrict__ t2b,
        const float* __restrict__ omw, const float* __restrict__ omb,
        const float* __restrict__ osw, const float* __restrict__ osb,
        const float* __restrict__ gaw, const float* __restrict__ gab,
        const float* __restrict__ gmw, const float* __restrict__ gmb,
        const float* __restrict__ gsw, const float* __restrict__ gsb,
        const float* __restrict__ zew, const float* __restrict__ zeb,
        const float* __restrict__ zmw, const float* __restrict__ zmb,
        const float* __restrict__ zsw, const float* __restrict__ zsb,
        float* __restrict__ out) {
    __shared__ __align__(16) float cst[256 * 36];
    __shared__ __align__(16) float a1t[128 * 36];
    __shared__ float ts[32 * 32];
    __shared__ float tv[128];
    __shared__ float eg_s[64], ez_s[64];
    __shared__ float red[256];
    __shared__ float redb[512];
    int tid = threadIdx.x;

    for (int i = tid; i < 32 * 256; i += 256) {
        int w = i >> 8, k = i & 255;
        cst[k * 36 + w] = cs_g[i];
    }
    __syncthreads();

    {   // GEMM1: a1 = relu(cs @ te2w1 + b1)   [32 x 128]
        int wg = tid >> 5, jg = tid & 31;
        int w0 = wg * 4, j0 = jg * 4;
        float acc[4][4] = {};
        for (int k = 0; k < 256; k++) {
            float4 cv4 = *(const float4*)&cst[k * 36 + w0];
            float4 wv4 = *(const float4*)&te2w1[k * 128 + j0];
            float cva[4] = {cv4.x, cv4.y, cv4.z, cv4.w};
            float wva[4] = {wv4.x, wv4.y, wv4.z, wv4.w};
            #pragma unroll
            for (int i = 0; i < 4; i++)
                #pragma unroll
                for (int j = 0; j < 4; j++)
                    acc[i][j] = fmaf(cva[i], wva[j], acc[i][j]);
        }
        #pragma unroll
        for (int jj = 0; jj < 4; jj++) {
            float b = te2b1[j0 + jj];
            #pragma unroll
            for (int i = 0; i < 4; i++)
                a1t[(j0 + jj) * 36 + w0 + i] = fmaxf(acc[i][jj] + b, 0.f);
        }
    }
    __syncthreads();

    {   // GEMM2: ts = a1 @ te2w2 + b2   [32 x 32]
        int wg = tid >> 4, jg = tid & 15;
        int w0 = wg * 2, j0 = jg * 2;
        float acc[2][2] = {};
        for (int k = 0; k < 128; k++) {
            float2 a2 = *(const float2*)&a1t[k * 36 + w0];
            float2 b2v = *(const float2*)&te2w2[k * 32 + j0];
            acc[0][0] = fmaf(a2.x, b2v.x, acc[0][0]);
            acc[0][1] = fmaf(a2.x, b2v.y, acc[0][1]);
            acc[1][0] = fmaf(a2.y, b2v.x, acc[1][0]);
            acc[1][1] = fmaf(a2.y, b2v.y, acc[1][1]);
        }
        #pragma unroll
        for (int i = 0; i < 2; i++)
            #pragma unroll
            for (int j = 0; j < 2; j++)
                ts[(w0 + i) * 32 + (j0 + j)] = acc[i][j] + te2b2[j0 + j];
    }

    // ---- omega partials: 32 w x 8 k-parts over all 256 threads ----
    {
        int w = tid & 31, part = tid >> 5;
        int k0 = part * 32;
        float am = 0.f, as = 0.f;
        #pragma unroll 4
        for (int k = k0; k < k0 + 32; k++) {
            float cv = cst[k * 36 + w];
            am = fmaf(cv, omw[k], am);
            as = fmaf(cv, osw[k], as);
        }
        redb[part * 32 + w] = am;
        redb[256 + part * 32 + w] = as;
    }
    __syncthreads();

    float muo = 0.f, sdo = 1.f;
    if (tid < 32) {
        // omega finish
        float am = 0.f, as = 0.f;
        #pragma unroll
        for (int p = 0; p < 8; p++) {
            am += redb[p * 32 + tid];
            as += redb[256 + p * 32 + tid];
        }
        muo = fmaxf(am + omb[0], 0.f);
        sdo = softplus_f(fmaxf(as + osb[0], 0.f));
        out[tid] = muo;
    } else if (tid < 64) {
        // t stats -> tv
        int t_ = tid - 32;
        float csum = 0.f;
        for (int w2 = 0; w2 < 32; w2++) csum += card[w2];
        float s = 0.f, s2 = 0.f;
        for (int w2 = 0; w2 < 32; w2++) { float v = ts[w2 * 32 + t_]; s += v; s2 += v * v; }
        float m  = s / 32.f;
        float vv = (s2 - s * s / 32.f) / 31.f;
        #pragma unroll
        for (int j = 0; j < 4; j++)
            tv[t_ * 4 + j] = fmaxf(m * t2w[j] + vv * t2w[4 + j] + csum * t2w[8 + j] + t2b[j], 0.f);
    }
    __syncthreads();

    // ---- gamma/zeta hidden layer: 64 j x 4 k-parts over all 256 threads ----
    {
        int j = tid & 63, part = tid >> 6;
        int k0 = part * 32;
        float ag = 0.f, az = 0.f;
        #pragma unroll 4
        for (int k = k0; k < k0 + 32; k++) {
            float t = tv[k];
            ag = fmaf(t, gaw[k * 64 + j], ag);
            az = fmaf(t, zew[k * 64 + j], az);
        }
        redb[part * 64 + j] = ag;
        redb[256 + part * 64 + j] = az;
    }
    __syncthreads();
    if (tid < 64) {
        float ag = gab[tid], az = zeb[tid];
        #pragma unroll
        for (int p = 0; p < 4; p++) {
            ag += redb[p * 64 + tid];
            az += redb[256 + p * 64 + tid];
        }
        eg_s[tid] = fmaxf(ag, 0.f);
        ez_s[tid] = fmaxf(az, 0.f);
    }
    __syncthreads();

    float r = 0.f;
    {
        int j = tid;
        float am = zmb[j], as = zsb[j];
        for (int k = 0; k < 64; k++) {
            float e = ez_s[k];
            am = fmaf(e, zmw[k * 256 + j], am);
            as = fmaf(e, zsw[k * 256 + j], as);
        }
        float mu = fmaxf(am, 0.f);
        float sd = softplus_f(fmaxf(as, 0.f));
        out[37 + j] = mu;
        r += kl_f(mu, sd);
    }
    if (tid < 5) {
        float am = gmb[tid], as = gsb[tid];
        for (int k = 0; k < 64; k++) {
            float e = eg_s[k];
            am = fmaf(e, gmw[k * 5 + tid], am);
            as = fmaf(e, gsw[k * 5 + tid], as);
        }
        float mu = fmaxf(am, 0.f);
        float sd = softplus_f(fmaxf(as, 0.f));
        out[32 + tid] = mu;
        r += kl_f(mu, sd);
    }
    if (tid < 32) r += kl_f(muo, sdo);   // omega KL lives in lanes 0..31
    red[tid] = r;
    __syncthreads();
    for (int s = 128; s > 0; s >>= 1) {
        if (tid < s) red[tid] += red[tid + s];
        __syncthreads();
    }
    if (tid == 0) out[293] = red[0];
}

// ---------------------------------------------------------------------------
extern "C" void kernel_launch(void* const* d_in, const int* in_sizes, int n_in,
                              void* d_out, int out_size, void* d_ws, size_t ws_size,
                              hipStream_t stream) {
    const float* x    = (const float*)d_in[0];
    const float* y    = (const float*)d_in[1];
    const float* w1   = (const float*)d_in[2];
    const float* b1   = (const float*)d_in[3];
    const float* w2   = (const float*)d_in[4];
    const float* b2   = (const float*)d_in[5];
    const float* encw = (const float*)d_in[6];
    const float* encb = (const float*)d_in[7];
    const float* t1w  = (const float*)d_in[8];
    const float* t1b  = (const float*)d_in[9];
    const float* te2w1 = (const float*)d_in[10];
    const float* te2b1 = (const float*)d_in[11];
    const float* te2w2 = (const float*)d_in[12];
    const float* te2b2 = (const float*)d_in[13];
    const float* t2w  = (const float*)d_in[14];
    const float* t2b  = (const float*)d_in[15];
    const float* omw  = (const float*)d_in[16];
    const float* omb  = (const float*)d_in[17];
    const float* osw  = (const float*)d_in[18];
    const float* osb  = (const float*)d_in[19];
    const float* gaw  = (const float*)d_in[20];
    const float* gab  = (const float*)d_in[21];
    const float* gmw  = (const float*)d_in[22];
    const float* gmb  = (const float*)d_in[23];
    const float* gsw  = (const float*)d_in[24];
    const float* gsb  = (const float*)d_in[25];
    const float* zew  = (const float*)d_in[26];
    const float* zeb  = (const float*)d_in[27];
    const float* zmw  = (const float*)d_in[28];
    const float* zmb  = (const float*)d_in[29];
    const float* zsw  = (const float*)d_in[30];
    const float* zsb  = (const float*)d_in[31];
    float* out = (float*)d_out;

    float* p2   = (float*)d_ws;                       // [2048][3610]
    float* H    = p2 + (size_t)NTOT * FLAT;           // [2048][64]
    int*   lbl  = (int*)(H + NTOT * 64);              // [2048]
    float* cs   = (float*)(lbl + NTOT);               // [32][256]
    float* card = cs + 32 * 256;                      // [32]

    hipMemsetAsync(H, 0, NTOT * 64 * sizeof(float), stream);
    hipLaunchKernelGGL(k_conv, dim3(NTOT * 10), dim3(256), 0, stream, x, w1, b1, w2, b2, p2);
    hipLaunchKernelGGL(k_label, dim3(8), dim3(256), 0, stream, y, lbl);
    hipLaunchKernelGGL(k_enc, dim3(32 * KSPLIT), dim3(256), 0, stream, p2, encw, H);
    hipLaunchKernelGGL(k_stats, dim3(32), dim3(1024), 0, stream, H, encb, lbl, t1w, t1b, cs, card);
    hipLaunchKernelGGL(k_head, dim3(1), dim3(256), 0, stream, cs, card,
                       te2w1, te2b1, te2w2, te2b2, t2w, t2b,
                       omw, omb, osw, osb, gaw, gab, gmw, gmb, gsw, gsb,
                       zew, zeb, zmw, zmb, zsw, zsb, out);
}

// Round 8
// 611.238 us; speedup vs baseline: 1.1145x; 1.1145x over previous
//
#include <hip/hip_runtime.h>
#include <math.h>

#define WAYS 32
#define NTOT 2048
#define XD 84
#define FLAT 3610
#define KSPLIT 16
#define KCHUNK 226  // ceil(3610/16)

__device__ __forceinline__ float softplus_f(float x) {
    return (x > 20.f) ? x : log1pf(expf(x));
}
__device__ __forceinline__ float kl_f(float mu, float sd) {
    return -logf(sd) + 0.5f * (sd * sd + mu * mu) - 0.5f;
}

// ---------------------------------------------------------------------------
// Fused conv1+relu+pool -> conv2+relu+pool.
// v6: 4 bands of 5 p2 rows (5,5,5,4) -- back to FAT bands (R7 lesson: small
// bands double fixed costs and trigger spill heuristics). Lane util: conv1
// 480/512=94%, conv2 190/256=74% (vs v2 78%/59%). p1s row stride 42 (not 40)
// to break conv2's 4-way bank conflict (80*pr % 32 in {0,16}).
// LDS = 26208+20160+1296+5760 = 53424 B -> 3 blocks/CU; launch_bounds(256,3)
// is the empirically spill-free config (VGPR 84, R2).
// ---------------------------------------------------------------------------
__global__ __launch_bounds__(256, 3) void k_conv(
        const float* __restrict__ x,
        const float* __restrict__ w1, const float* __restrict__ b1,
        const float* __restrict__ w2, const float* __restrict__ b2,
        float* __restrict__ p2) {
    __shared__ __align__(16) float xs[3 * 26 * 84];   // [c][row][col] 26208 B
    __shared__ __align__(16) float p1s[10 * 12 * 42]; // [ic][q][col pad42] 20160 B
    __shared__ __align__(16) float w1t[27 * 12];      // [c*9+k][oc(10) pad 12]
    __shared__ __align__(16) float w2t[90 * 16];      // [ic*9+k][h*8+o pad 16]

    const int tid  = threadIdx.x;
    const int img  = blockIdx.x & 2047;
    const int band = blockIdx.x >> 11;       // 0..3
    const int r0   = band * 5;               // first p2 row (0,5,10,15)
    const int nr   = (band < 3) ? 5 : 4;     // p2 rows in band
    const int nq   = 2 * nr + 2;             // p1 rows needed (12 or 10)
    const int xr0  = 4 * r0;                 // first x row (0,20,40,60)
    const int nxr  = 2 * nq + 2;             // x rows (26 or 22)

    // ---- stage x band (float4 copies; both sides 16B aligned) ----
    {
        const float* xg = x + (size_t)img * (3 * XD * XD);
        const int nv = (nxr * 84) >> 2;      // 546 or 462 float4s
        #pragma unroll
        for (int c = 0; c < 3; c++) {
            const float4* src = (const float4*)(xg + c * (XD * XD) + xr0 * 84);
            float4* dst = (float4*)(xs + c * (26 * 84));
            for (int i = tid; i < nv; i += 256) dst[i] = src[i];
        }
    }
    // ---- stage weights transposed (oc innermost) ----
    for (int i = tid; i < 270; i += 256) {
        int oc = i / 27, r = i - oc * 27;    // r = c*9 + ky*3 + kx
        w1t[r * 12 + oc] = w1[i];
    }
    for (int i = tid; i < 900; i += 256) {
        int oc = i / 90, r = i - oc * 90;    // r = ic*9 + ky*3 + kx
        int h = oc / 5, o = oc - h * 5;
        w2t[r * 16 + h * 8 + o] = w2[i];
    }
    float b1r[10];
    #pragma unroll
    for (int o = 0; o < 10; o++) b1r[o] = b1[o];
    __syncthreads();

    // ---- conv1 + relu + pool -> p1s (all 10 oc per item) ----
    {
        const int n1 = nq * 40;              // 480 or 400
        #pragma unroll 1
        for (int it = tid; it < n1; it += 256) {
            asm volatile("" ::: "memory");   // no load hoisting across iters
            int q = it / 40;                 // local p1 row
            int p = it - q * 40;             // p1 col
            float acc[10][4];
            #pragma unroll
            for (int o = 0; o < 10; o++)
                #pragma unroll
                for (int j = 0; j < 4; j++) acc[o][j] = 0.f;
            #pragma unroll 1
            for (int c = 0; c < 3; c++) {
                float xp[4][4];
                #pragma unroll
                for (int rr = 0; rr < 4; rr++) {
                    const float2* row =
                        (const float2*)&xs[c * (26 * 84) + (2 * q + rr) * 84 + 2 * p];
                    float2 lo = row[0], hi = row[1];
                    xp[rr][0] = lo.x; xp[rr][1] = lo.y;
                    xp[rr][2] = hi.x; xp[rr][3] = hi.y;
                }
                #pragma unroll
                for (int ky = 0; ky < 3; ky++) {
                    #pragma unroll
                    for (int kx = 0; kx < 3; kx++) {
                        const float* wr = &w1t[(c * 9 + ky * 3 + kx) * 12];
                        float4 wA = *(const float4*)(wr);
                        float4 wB = *(const float4*)(wr + 4);
                        float2 wC = *(const float2*)(wr + 8);
                        float wv[10] = {wA.x, wA.y, wA.z, wA.w,
                                        wB.x, wB.y, wB.z, wB.w,
                                        wC.x, wC.y};
                        #pragma unroll
                        for (int o = 0; o < 10; o++) {
                            float w = wv[o];
                            acc[o][0] = fmaf(xp[ky][kx],         w, acc[o][0]);
                            acc[o][1] = fmaf(xp[ky][kx + 1],     w, acc[o][1]);
                            acc[o][2] = fmaf(xp[ky + 1][kx],     w, acc[o][2]);
                            acc[o][3] = fmaf(xp[ky + 1][kx + 1], w, acc[o][3]);
                        }
                    }
                }
            }
            #pragma unroll
            for (int o = 0; o < 10; o++) {
                float m = fmaxf(fmaxf(acc[o][0], acc[o][1]), fmaxf(acc[o][2], acc[o][3]));
                p1s[o * 504 + q * 42 + p] = fmaxf(m + b1r[o], 0.f);
            }
        }
    }
    __syncthreads();

    // ---- conv2 + relu + pool -> p2 (global) ----
    {
        const int npos = nr * 19;            // 95 or 76
        if (tid < 2 * npos) {
            int half = (tid >= npos) ? 1 : 0;
            int pos  = tid - npos * half;
            int pr = pos / 19;               // local p2 row
            int pc = pos - pr * 19;
            float acc[5][4];
            #pragma unroll
            for (int o = 0; o < 5; o++)
                #pragma unroll
                for (int j = 0; j < 4; j++) acc[o][j] = 0.f;
            #pragma unroll 1
            for (int ic = 0; ic < 10; ic++) {
                float xp[4][4];
                #pragma unroll
                for (int rr = 0; rr < 4; rr++) {
                    const float2* row =
                        (const float2*)&p1s[ic * 504 + (2 * pr + rr) * 42 + 2 * pc];
                    float2 lo = row[0], hi = row[1];
                    xp[rr][0] = lo.x; xp[rr][1] = lo.y;
                    xp[rr][2] = hi.x; xp[rr][3] = hi.y;
                }
                #pragma unroll
                for (int ky = 0; ky < 3; ky++) {
                    #pragma unroll
                    for (int kx = 0; kx < 3; kx++) {
                        const float* wr = &w2t[(ic * 9 + ky * 3 + kx) * 16 + half * 8];
                        float4 wA = *(const float4*)(wr);
                        float w4 = wr[4];
                        float wv[5] = {wA.x, wA.y, wA.z, wA.w, w4};
                        #pragma unroll
                        for (int o = 0; o < 5; o++) {
                            float w = wv[o];
                            acc[o][0] = fmaf(xp[ky][kx],         w, acc[o][0]);
                            acc[o][1] = fmaf(xp[ky][kx + 1],     w, acc[o][1]);
                            acc[o][2] = fmaf(xp[ky + 1][kx],     w, acc[o][2]);
                            acc[o][3] = fmaf(xp[ky + 1][kx + 1], w, acc[o][3]);
                        }
                    }
                }
            }
            float* outp = p2 + (size_t)img * FLAT;
            #pragma unroll
            for (int o = 0; o < 5; o++) {
                int oc = half * 5 + o;
                float m = fmaxf(fmaxf(acc[o][0], acc[o][1]), fmaxf(acc[o][2], acc[o][3]));
                outp[oc * 361 + (r0 + pr) * 19 + pc] = fmaxf(m + b2[oc], 0.f);
            }
        }
    }
}

// ---------------------------------------------------------------------------
// enc GEMM: H[2048,64] += p2[2048,3610] @ enc_w[3610,64]  (split-K, atomics)
// a_s stride 68 (16B-aligned rows) -> both operands load as float4.
// ---------------------------------------------------------------------------
__global__ __launch_bounds__(256, 2) void k_enc(
        const float* __restrict__ A, const float* __restrict__ W,
        float* __restrict__ H) {
    __shared__ __align__(16) float a_s[32 * 68];
    __shared__ __align__(16) float w_s[32 * 64];
    int mb = blockIdx.x >> 4;
    int ks = blockIdx.x & 15;
    int row0 = mb * 64;
    int kbeg = ks * KCHUNK;
    int kend = min(kbeg + KCHUNK, FLAT);
    int tid = threadIdx.x;
    int tr = tid & 15, tc = tid >> 4;
    float acc[4][4] = {};

    for (int k0 = kbeg; k0 < kend; k0 += 32) {
        {
            int kk = tid & 31;
            int r  = tid >> 5;
            int gk = k0 + kk;
            #pragma unroll
            for (int i = 0; i < 8; i++) {
                int rr = r + i * 8;
                float v = (gk < kend) ? A[(size_t)(row0 + rr) * FLAT + gk] : 0.f;
                a_s[kk * 68 + rr] = v;
            }
            int c  = tid & 63;
            int kw = tid >> 6;
            #pragma unroll
            for (int i = 0; i < 8; i++) {
                int kk2 = kw + i * 4;
                int gk2 = k0 + kk2;
                float v = (gk2 < kend) ? W[(size_t)gk2 * 64 + c] : 0.f;
                w_s[kk2 * 64 + c] = v;
            }
        }
        __syncthreads();
        #pragma unroll 8
        for (int k = 0; k < 32; k++) {
            float4 av4 = *(const float4*)&a_s[k * 68 + tr * 4];
            float4 wv4 = *(const float4*)&w_s[k * 64 + tc * 4];
            float av[4] = {av4.x, av4.y, av4.z, av4.w};
            float wv[4] = {wv4.x, wv4.y, wv4.z, wv4.w};
            #pragma unroll
            for (int i = 0; i < 4; i++)
                #pragma unroll
                for (int j = 0; j < 4; j++)
                    acc[i][j] = fmaf(av[i], wv[j], acc[i][j]);
        }
        __syncthreads();
    }
    #pragma unroll
    for (int i = 0; i < 4; i++)
        #pragma unroll
        for (int j = 0; j < 4; j++)
            atomicAdd(&H[(size_t)(row0 + tr * 4 + i) * 64 + tc * 4 + j], acc[i][j]);
}

// ---------------------------------------------------------------------------
// v3: k_label fused in (each block computes all 2048 argmaxes itself, ~2us
// redundant, saves a kernel launch + global label round-trip).
// labels in LDS, branchless masked accumulation, 1024 threads.
// ---------------------------------------------------------------------------
__global__ __launch_bounds__(1024) void k_stats(
        const float* __restrict__ H, const float* __restrict__ encb,
        const float* __restrict__ y,
        const float* __restrict__ t1w, const float* __restrict__ t1b,
        float* __restrict__ cs, float* __restrict__ card) {
    __shared__ int   lbl_s[NTOT];
    __shared__ float rs[16][64], rs2[16][64];
    __shared__ int rc[16];
    int w = blockIdx.x;
    int tid = threadIdx.x;
    for (int n = tid; n < NTOT; n += 1024) {
        const float* yr = y + n * WAYS;
        float best = yr[0]; int bi = 0;
        #pragma unroll
        for (int k = 1; k < WAYS; k++) {
            float v = yr[k];
            if (v > best) { best = v; bi = k; }
        }
        lbl_s[n] = bi;
    }
    __syncthreads();
    int c = tid & 63, g = tid >> 6;          // g in 0..15
    float eb = encb[c];
    float s = 0.f, s2 = 0.f; int cnt = 0;
    #pragma unroll 4
    for (int n = g; n < NTOT; n += 16) {
        bool m = (lbl_s[n] == w);
        float hv = H[n * 64 + c] + eb;
        float hm = m ? hv : 0.f;
        s += hm; s2 += hm * hm; cnt += m ? 1 : 0;
    }
    rs[g][c] = s; rs2[g][c] = s2;
    if (c == 0) rc[g] = cnt;
    __syncthreads();
    if (g == 0) {
        float S = 0.f, S2 = 0.f; int CNT = 0;
        #pragma unroll
        for (int gg = 0; gg < 16; gg++) {
            S += rs[gg][c]; S2 += rs2[gg][c]; CNT += rc[gg];
        }
        float mean = S / 2048.f;
        float var  = (S2 - S * S / 2048.f) / 2047.f;
        float cd   = ((float)CNT - 1.f) / 63.f;
        #pragma unroll
        for (int j = 0; j < 4; j++)
            cs[w * 256 + c * 4 + j] =
                fmaxf(mean * t1w[j] + var * t1w[4 + j] + cd * t1w[8 + j] + t1b[j], 0.f);
        if (c == 0) card[w] = cd;
    }
}

// ---------------------------------------------------------------------------
// omega spread over 256 threads (8-way k-split), gamma/zeta input layer
// spread over 256 threads (4-way k-split), vectorized GEMM operand loads.
// ---------------------------------------------------------------------------
__global__ __launch_bounds__(256) void k_head(
        const float* __restrict__ cs_g, const float* __restrict__ card,
        const float* __restrict__ te2w1, const float* __restrict__ te2b1,
        const float* __restrict__ te2w2, const float* __restrict__ te2b2,
        const float* __restrict__ t2w, const float* __restrict__ t2b,
        const float* __restrict__ omw, const float* __restrict__ omb,
        const float* __restrict__ osw, const float* __restrict__ osb,
        const float* __restrict__ gaw, const float* __restrict__ gab,
        const float* __restrict__ gmw, const float* __restrict__ gmb,
        const float* __restrict__ gsw, const float* __restrict__ gsb,
        const float* __restrict__ zew, const float* __restrict__ zeb,
        const float* __restrict__ zmw, const float* __restrict__ zmb,
        const float* __restrict__ zsw, const float* __restrict__ zsb,
        float* __restrict__ out) {
    __shared__ __align__(16) float cst[256 * 36];
    __shared__ __align__(16) float a1t[128 * 36];
    __shared__ float ts[32 * 32];
    __shared__ float tv[128];
    __shared__ float eg_s[64], ez_s[64];
    __shared__ float red[256];
    __shared__ float redb[512];
    int tid = threadIdx.x;

    for (int i = tid; i < 32 * 256; i += 256) {
        int w = i >> 8, k = i & 255;
        cst[k * 36 + w] = cs_g[i];
    }
    __syncthreads();

    {   // GEMM1: a1 = relu(cs @ te2w1 + b1)   [32 x 128]
        int wg = tid >> 5, jg = tid & 31;
        int w0 = wg * 4, j0 = jg * 4;
        float acc[4][4] = {};
        for (int k = 0; k < 256; k++) {
            float4 cv4 = *(const float4*)&cst[k * 36 + w0];
            float4 wv4 = *(const float4*)&te2w1[k * 128 + j0];
            float cva[4] = {cv4.x, cv4.y, cv4.z, cv4.w};
            float wva[4] = {wv4.x, wv4.y, wv4.z, wv4.w};
            #pragma unroll
            for (int i = 0; i < 4; i++)
                #pragma unroll
                for (int j = 0; j < 4; j++)
                    acc[i][j] = fmaf(cva[i], wva[j], acc[i][j]);
        }
        #pragma unroll
        for (int jj = 0; jj < 4; jj++) {
            float b = te2b1[j0 + jj];
            #pragma unroll
            for (int i = 0; i < 4; i++)
                a1t[(j0 + jj) * 36 + w0 + i] = fmaxf(acc[i][jj] + b, 0.f);
        }
    }
    __syncthreads();

    {   // GEMM2: ts = a1 @ te2w2 + b2   [32 x 32]
        int wg = tid >> 4, jg = tid & 15;
        int w0 = wg * 2, j0 = jg * 2;
        float acc[2][2] = {};
        for (int k = 0; k < 128; k++) {
            float2 a2 = *(const float2*)&a1t[k * 36 + w0];
            float2 b2v = *(const float2*)&te2w2[k * 32 + j0];
            acc[0][0] = fmaf(a2.x, b2v.x, acc[0][0]);
            acc[0][1] = fmaf(a2.x, b2v.y, acc[0][1]);
            acc[1][0] = fmaf(a2.y, b2v.x, acc[1][0]);
            acc[1][1] = fmaf(a2.y, b2v.y, acc[1][1]);
        }
        #pragma unroll
        for (int i = 0; i < 2; i++)
            #pragma unroll
            for (int j = 0; j < 2; j++)
                ts[(w0 + i) * 32 + (j0 + j)] = acc[i][j] + te2b2[j0 + j];
    }

    // ---- omega partials: 32 w x 8 k-parts over all 256 threads ----
    {
        int w = tid & 31, part = tid >> 5;
        int k0 = part * 32;
        float am = 0.f, as = 0.f;
        #pragma unroll 4
        for (int k = k0; k < k0 + 32; k++) {
            float cv = cst[k * 36 + w];
            am = fmaf(cv, omw[k], am);
            as = fmaf(cv, osw[k], as);
        }
        redb[part * 32 + w] = am;
        redb[256 + part * 32 + w] = as;
    }
    __syncthreads();

    float muo = 0.f, sdo = 1.f;
    if (tid < 32) {
        // omega finish
        float am = 0.f, as = 0.f;
        #pragma unroll
        for (int p = 0; p < 8; p++) {
            am += redb[p * 32 + tid];
            as += redb[256 + p * 32 + tid];
        }
        muo = fmaxf(am + omb[0], 0.f);
        sdo = softplus_f(fmaxf(as + osb[0], 0.f));
        out[tid] = muo;
    } else if (tid < 64) {
        // t stats -> tv
        int t_ = tid - 32;
        float csum = 0.f;
        for (int w2 = 0; w2 < 32; w2++) csum += card[w2];
        float s = 0.f, s2 = 0.f;
        for (int w2 = 0; w2 < 32; w2++) { float v = ts[w2 * 32 + t_]; s += v; s2 += v * v; }
        float m  = s / 32.f;
        float vv = (s2 - s * s / 32.f) / 31.f;
        #pragma unroll
        for (int j = 0; j < 4; j++)
            tv[t_ * 4 + j] = fmaxf(m * t2w[j] + vv * t2w[4 + j] + csum * t2w[8 + j] + t2b[j], 0.f);
    }
    __syncthreads();

    // ---- gamma/zeta hidden layer: 64 j x 4 k-parts over all 256 threads ----
    {
        int j = tid & 63, part = tid >> 6;
        int k0 = part * 32;
        float ag = 0.f, az = 0.f;
        #pragma unroll 4
        for (int k = k0; k < k0 + 32; k++) {
            float t = tv[k];
            ag = fmaf(t, gaw[k * 64 + j], ag);
            az = fmaf(t, zew[k * 64 + j], az);
        }
        redb[part * 64 + j] = ag;
        redb[256 + part * 64 + j] = az;
    }
    __syncthreads();
    if (tid < 64) {
        float ag = gab[tid], az = zeb[tid];
        #pragma unroll
        for (int p = 0; p < 4; p++) {
            ag += redb[p * 64 + tid];
            az += redb[256 + p * 64 + tid];
        }
        eg_s[tid] = fmaxf(ag, 0.f);
        ez_s[tid] = fmaxf(az, 0.f);
    }
    __syncthreads();

    float r = 0.f;
    {
        int j = tid;
        float am = zmb[j], as = zsb[j];
        for (int k = 0; k < 64; k++) {
            float e = ez_s[k];
            am = fmaf(e, zmw[k * 256 + j], am);
            as = fmaf(e, zsw[k * 256 + j], as);
        }
        float mu = fmaxf(am, 0.f);
        float sd = softplus_f(fmaxf(as, 0.f));
        out[37 + j] = mu;
        r += kl_f(mu, sd);
    }
    if (tid < 5) {
        float am = gmb[tid], as = gsb[tid];
        for (int k = 0; k < 64; k++) {
            float e = eg_s[k];
            am = fmaf(e, gmw[k * 5 + tid], am);
            as = fmaf(e, gsw[k * 5 + tid], as);
        }
        float mu = fmaxf(am, 0.f);
        float sd = softplus_f(fmaxf(as, 0.f));
        out[32 + tid] = mu;
        r += kl_f(mu, sd);
    }
    if (tid < 32) r += kl_f(muo, sdo);   // omega KL lives in lanes 0..31
    red[tid] = r;
    __syncthreads();
    for (int s = 128; s > 0; s >>= 1) {
        if (tid < s) red[tid] += red[tid + s];
        __syncthreads();
    }
    if (tid == 0) out[293] = red[0];
}

// ---------------------------------------------------------------------------
extern "C" void kernel_launch(void* const* d_in, const int* in_sizes, int n_in,
                              void* d_out, int out_size, void* d_ws, size_t ws_size,
                              hipStream_t stream) {
    const float* x    = (const float*)d_in[0];
    const float* y    = (const float*)d_in[1];
    const float* w1   = (const float*)d_in[2];
    const float* b1   = (const float*)d_in[3];
    const float* w2   = (const float*)d_in[4];
    const float* b2   = (const float*)d_in[5];
    const float* encw = (const float*)d_in[6];
    const float* encb = (const float*)d_in[7];
    const float* t1w  = (const float*)d_in[8];
    const float* t1b  = (const float*)d_in[9];
    const float* te2w1 = (const float*)d_in[10];
    const float* te2b1 = (const float*)d_in[11];
    const float* te2w2 = (const float*)d_in[12];
    const float* te2b2 = (const float*)d_in[13];
    const float* t2w  = (const float*)d_in[14];
    const float* t2b  = (const float*)d_in[15];
    const float* omw  = (const float*)d_in[16];
    const float* omb  = (const float*)d_in[17];
    const float* osw  = (const float*)d_in[18];
    const float* osb  = (const float*)d_in[19];
    const float* gaw  = (const float*)d_in[20];
    const float* gab  = (const float*)d_in[21];
    const float* gmw  = (const float*)d_in[22];
    const float* gmb  = (const float*)d_in[23];
    const float* gsw  = (const float*)d_in[24];
    const float* gsb  = (const float*)d_in[25];
    const float* zew  = (const float*)d_in[26];
    const float* zeb  = (const float*)d_in[27];
    const float* zmw  = (const float*)d_in[28];
    const float* zmb  = (const float*)d_in[29];
    const float* zsw  = (const float*)d_in[30];
    const float* zsb  = (const float*)d_in[31];
    float* out = (float*)d_out;

    float* p2   = (float*)d_ws;                       // [2048][3610]
    float* H    = p2 + (size_t)NTOT * FLAT;           // [2048][64]
    int*   lbl  = (int*)(H + NTOT * 64);              // [2048] (unused, layout kept)
    float* cs   = (float*)(lbl + NTOT);               // [32][256]
    float* card = cs + 32 * 256;                      // [32]

    hipMemsetAsync(H, 0, NTOT * 64 * sizeof(float), stream);
    hipLaunchKernelGGL(k_conv, dim3(NTOT * 4), dim3(256), 0, stream, x, w1, b1, w2, b2, p2);
    hipLaunchKernelGGL(k_enc, dim3(32 * KSPLIT), dim3(256), 0, stream, p2, encw, H);
    hipLaunchKernelGGL(k_stats, dim3(32), dim3(1024), 0, stream, H, encb, y, t1w, t1b, cs, card);
    hipLaunchKernelGGL(k_head, dim3(1), dim3(256), 0, stream, cs, card,
                       te2w1, te2b1, te2w2, te2b2, t2w, t2b,
                       omw, omb, osw, osb, gaw, gab, gmw, gmb, gsw, gsb,
                       zew, zeb, zmw, zmb, zsw, zsb, out);
}

// Round 9
// 590.595 us; speedup vs baseline: 1.1535x; 1.0350x over previous
//
#include <hip/hip_runtime.h>
#include <math.h>

#define WAYS 32
#define NTOT 2048
#define XD 84
#define FLAT 3610
#define KSPLIT 16
#define KCHUNK 226  // ceil(3610/16)

__device__ __forceinline__ float softplus_f(float x) {
    return (x > 20.f) ? x : log1pf(expf(x));
}
__device__ __forceinline__ float kl_f(float mu, float sd) {
    return -logf(sd) + 0.5f * (sd * sd + mu * mu) - 0.5f;
}

// ---------------------------------------------------------------------------
// Fused conv1+relu+pool -> conv2+relu+pool.
// v7: v6's 4 fat bands (5,5,5,4 p2 rows) but NO xs staging -- conv1 reads x
// directly from global (per-row-contiguous float2, L2/L3-resident window).
// LDS = p1s 20160 + w1t 1296 + w2t 5760 = 27216 B -> 5 blocks/CU at VGPR 84
// under the proven (256,4) cap ((256,5) = R6 allocator collapse).
// Kills conv1's LDS bank conflicts (R8: stride-42 pad didn't move the 2.2e7
// counter -> conflicts were conv1 xs reads) and one barrier + staging phase.
// ---------------------------------------------------------------------------
__global__ __launch_bounds__(256, 4) void k_conv(
        const float* __restrict__ x,
        const float* __restrict__ w1, const float* __restrict__ b1,
        const float* __restrict__ w2, const float* __restrict__ b2,
        float* __restrict__ p2) {
    __shared__ __align__(16) float p1s[10 * 12 * 42]; // [ic][q][col pad42] 20160 B
    __shared__ __align__(16) float w1t[27 * 12];      // [c*9+k][oc(10) pad 12]
    __shared__ __align__(16) float w2t[90 * 16];      // [ic*9+k][h*8+o pad 16]

    const int tid  = threadIdx.x;
    const int img  = blockIdx.x & 2047;
    const int band = blockIdx.x >> 11;       // 0..3
    const int r0   = band * 5;               // first p2 row (0,5,10,15)
    const int nr   = (band < 3) ? 5 : 4;     // p2 rows in band
    const int nq   = 2 * nr + 2;             // p1 rows needed (12 or 10)
    const int xr0  = 4 * r0;                 // first x row (0,20,40,60)

    // ---- stage weights transposed (oc innermost) ----
    for (int i = tid; i < 270; i += 256) {
        int oc = i / 27, r = i - oc * 27;    // r = c*9 + ky*3 + kx
        w1t[r * 12 + oc] = w1[i];
    }
    for (int i = tid; i < 900; i += 256) {
        int oc = i / 90, r = i - oc * 90;    // r = ic*9 + ky*3 + kx
        int h = oc / 5, o = oc - h * 5;
        w2t[r * 16 + h * 8 + o] = w2[i];
    }
    float b1r[10];
    #pragma unroll
    for (int o = 0; o < 10; o++) b1r[o] = b1[o];
    __syncthreads();

    // band-local x base: row (2q+rr) col 2p in band coords
    const float* xb = x + (size_t)img * (3 * XD * XD) + xr0 * 84;

    // ---- conv1 + relu + pool -> p1s (all 10 oc per item, x from global) ----
    {
        const int n1 = nq * 40;              // 480 or 400
        #pragma unroll 1
        for (int it = tid; it < n1; it += 256) {
            asm volatile("" ::: "memory");   // no load hoisting across iters
            int q = it / 40;                 // local p1 row
            int p = it - q * 40;             // p1 col
            float acc[10][4];
            #pragma unroll
            for (int o = 0; o < 10; o++)
                #pragma unroll
                for (int j = 0; j < 4; j++) acc[o][j] = 0.f;
            #pragma unroll 1
            for (int c = 0; c < 3; c++) {
                float xp[4][4];
                #pragma unroll
                for (int rr = 0; rr < 4; rr++) {
                    const float2* row =
                        (const float2*)&xb[c * (XD * XD) + (2 * q + rr) * 84 + 2 * p];
                    float2 lo = row[0], hi = row[1];
                    xp[rr][0] = lo.x; xp[rr][1] = lo.y;
                    xp[rr][2] = hi.x; xp[rr][3] = hi.y;
                }
                #pragma unroll
                for (int ky = 0; ky < 3; ky++) {
                    #pragma unroll
                    for (int kx = 0; kx < 3; kx++) {
                        const float* wr = &w1t[(c * 9 + ky * 3 + kx) * 12];
                        float4 wA = *(const float4*)(wr);
                        float4 wB = *(const float4*)(wr + 4);
                        float2 wC = *(const float2*)(wr + 8);
                        float wv[10] = {wA.x, wA.y, wA.z, wA.w,
                                        wB.x, wB.y, wB.z, wB.w,
                                        wC.x, wC.y};
                        #pragma unroll
                        for (int o = 0; o < 10; o++) {
                            float w = wv[o];
                            acc[o][0] = fmaf(xp[ky][kx],         w, acc[o][0]);
                            acc[o][1] = fmaf(xp[ky][kx + 1],     w, acc[o][1]);
                            acc[o][2] = fmaf(xp[ky + 1][kx],     w, acc[o][2]);
                            acc[o][3] = fmaf(xp[ky + 1][kx + 1], w, acc[o][3]);
                        }
                    }
                }
            }
            #pragma unroll
            for (int o = 0; o < 10; o++) {
                float m = fmaxf(fmaxf(acc[o][0], acc[o][1]), fmaxf(acc[o][2], acc[o][3]));
                p1s[o * 504 + q * 42 + p] = fmaxf(m + b1r[o], 0.f);
            }
        }
    }
    __syncthreads();

    // ---- conv2 + relu + pool -> p2 (global) ----
    {
        const int npos = nr * 19;            // 95 or 76
        if (tid < 2 * npos) {
            int half = (tid >= npos) ? 1 : 0;
            int pos  = tid - npos * half;
            int pr = pos / 19;               // local p2 row
            int pc = pos - pr * 19;
            float acc[5][4];
            #pragma unroll
            for (int o = 0; o < 5; o++)
                #pragma unroll
                for (int j = 0; j < 4; j++) acc[o][j] = 0.f;
            #pragma unroll 1
            for (int ic = 0; ic < 10; ic++) {
                float xp[4][4];
                #pragma unroll
                for (int rr = 0; rr < 4; rr++) {
                    const float2* row =
                        (const float2*)&p1s[ic * 504 + (2 * pr + rr) * 42 + 2 * pc];
                    float2 lo = row[0], hi = row[1];
                    xp[rr][0] = lo.x; xp[rr][1] = lo.y;
                    xp[rr][2] = hi.x; xp[rr][3] = hi.y;
                }
                #pragma unroll
                for (int ky = 0; ky < 3; ky++) {
                    #pragma unroll
                    for (int kx = 0; kx < 3; kx++) {
                        const float* wr = &w2t[(ic * 9 + ky * 3 + kx) * 16 + half * 8];
                        float4 wA = *(const float4*)(wr);
                        float w4 = wr[4];
                        float wv[5] = {wA.x, wA.y, wA.z, wA.w, w4};
                        #pragma unroll
                        for (int o = 0; o < 5; o++) {
                            float w = wv[o];
                            acc[o][0] = fmaf(xp[ky][kx],         w, acc[o][0]);
                            acc[o][1] = fmaf(xp[ky][kx + 1],     w, acc[o][1]);
                            acc[o][2] = fmaf(xp[ky + 1][kx],     w, acc[o][2]);
                            acc[o][3] = fmaf(xp[ky + 1][kx + 1], w, acc[o][3]);
                        }
                    }
                }
            }
            float* outp = p2 + (size_t)img * FLAT;
            #pragma unroll
            for (int o = 0; o < 5; o++) {
                int oc = half * 5 + o;
                float m = fmaxf(fmaxf(acc[o][0], acc[o][1]), fmaxf(acc[o][2], acc[o][3]));
                outp[oc * 361 + (r0 + pr) * 19 + pc] = fmaxf(m + b2[oc], 0.f);
            }
        }
    }
}

// ---------------------------------------------------------------------------
// enc GEMM: H[2048,64] += p2[2048,3610] @ enc_w[3610,64]  (split-K, atomics)
// a_s stride 68 (16B-aligned rows) -> both operands load as float4.
// ---------------------------------------------------------------------------
__global__ __launch_bounds__(256, 2) void k_enc(
        const float* __restrict__ A, const float* __restrict__ W,
        float* __restrict__ H) {
    __shared__ __align__(16) float a_s[32 * 68];
    __shared__ __align__(16) float w_s[32 * 64];
    int mb = blockIdx.x >> 4;
    int ks = blockIdx.x & 15;
    int row0 = mb * 64;
    int kbeg = ks * KCHUNK;
    int kend = min(kbeg + KCHUNK, FLAT);
    int tid = threadIdx.x;
    int tr = tid & 15, tc = tid >> 4;
    float acc[4][4] = {};

    for (int k0 = kbeg; k0 < kend; k0 += 32) {
        {
            int kk = tid & 31;
            int r  = tid >> 5;
            int gk = k0 + kk;
            #pragma unroll
            for (int i = 0; i < 8; i++) {
                int rr = r + i * 8;
                float v = (gk < kend) ? A[(size_t)(row0 + rr) * FLAT + gk] : 0.f;
                a_s[kk * 68 + rr] = v;
            }
            int c  = tid & 63;
            int kw = tid >> 6;
            #pragma unroll
            for (int i = 0; i < 8; i++) {
                int kk2 = kw + i * 4;
                int gk2 = k0 + kk2;
                float v = (gk2 < kend) ? W[(size_t)gk2 * 64 + c] : 0.f;
                w_s[kk2 * 64 + c] = v;
            }
        }
        __syncthreads();
        #pragma unroll 8
        for (int k = 0; k < 32; k++) {
            float4 av4 = *(const float4*)&a_s[k * 68 + tr * 4];
            float4 wv4 = *(const float4*)&w_s[k * 64 + tc * 4];
            float av[4] = {av4.x, av4.y, av4.z, av4.w};
            float wv[4] = {wv4.x, wv4.y, wv4.z, wv4.w};
            #pragma unroll
            for (int i = 0; i < 4; i++)
                #pragma unroll
                for (int j = 0; j < 4; j++)
                    acc[i][j] = fmaf(av[i], wv[j], acc[i][j]);
        }
        __syncthreads();
    }
    #pragma unroll
    for (int i = 0; i < 4; i++)
        #pragma unroll
        for (int j = 0; j < 4; j++)
            atomicAdd(&H[(size_t)(row0 + tr * 4 + i) * 64 + tc * 4 + j], acc[i][j]);
}

// ---------------------------------------------------------------------------
// k_label fused in; labels in LDS, branchless masked accumulation, 1024 thr.
// ---------------------------------------------------------------------------
__global__ __launch_bounds__(1024) void k_stats(
        const float* __restrict__ H, const float* __restrict__ encb,
        const float* __restrict__ y,
        const float* __restrict__ t1w, const float* __restrict__ t1b,
        float* __restrict__ cs, float* __restrict__ card) {
    __shared__ int   lbl_s[NTOT];
    __shared__ float rs[16][64], rs2[16][64];
    __shared__ int rc[16];
    int w = blockIdx.x;
    int tid = threadIdx.x;
    for (int n = tid; n < NTOT; n += 1024) {
        const float* yr = y + n * WAYS;
        float best = yr[0]; int bi = 0;
        #pragma unroll
        for (int k = 1; k < WAYS; k++) {
            float v = yr[k];
            if (v > best) { best = v; bi = k; }
        }
        lbl_s[n] = bi;
    }
    __syncthreads();
    int c = tid & 63, g = tid >> 6;          // g in 0..15
    float eb = encb[c];
    float s = 0.f, s2 = 0.f; int cnt = 0;
    #pragma unroll 4
    for (int n = g; n < NTOT; n += 16) {
        bool m = (lbl_s[n] == w);
        float hv = H[n * 64 + c] + eb;
        float hm = m ? hv : 0.f;
        s += hm; s2 += hm * hm; cnt += m ? 1 : 0;
    }
    rs[g][c] = s; rs2[g][c] = s2;
    if (c == 0) rc[g] = cnt;
    __syncthreads();
    if (g == 0) {
        float S = 0.f, S2 = 0.f; int CNT = 0;
        #pragma unroll
        for (int gg = 0; gg < 16; gg++) {
            S += rs[gg][c]; S2 += rs2[gg][c]; CNT += rc[gg];
        }
        float mean = S / 2048.f;
        float var  = (S2 - S * S / 2048.f) / 2047.f;
        float cd   = ((float)CNT - 1.f) / 63.f;
        #pragma unroll
        for (int j = 0; j < 4; j++)
            cs[w * 256 + c * 4 + j] =
                fmaxf(mean * t1w[j] + var * t1w[4 + j] + cd * t1w[8 + j] + t1b[j], 0.f);
        if (c == 0) card[w] = cd;
    }
}

// ---------------------------------------------------------------------------
// omega spread over 256 threads (8-way k-split), gamma/zeta input layer
// spread over 256 threads (4-way k-split), vectorized GEMM operand loads.
// ---------------------------------------------------------------------------
__global__ __launch_bounds__(256) void k_head(
        const float* __restrict__ cs_g, const float* __restrict__ card,
        const float* __restrict__ te2w1, const float* __restrict__ te2b1,
        const float* __restrict__ te2w2, const float* __restrict__ te2b2,
        const float* __restrict__ t2w, const float* __restrict__ t2b,
        const float* __restrict__ omw, const float* __restrict__ omb,
        const float* __restrict__ osw, const float* __restrict__ osb,
        const float* __restrict__ gaw, const float* __restrict__ gab,
        const float* __restrict__ gmw, const float* __restrict__ gmb,
        const float* __restrict__ gsw, const float* __restrict__ gsb,
        const float* __restrict__ zew, const float* __restrict__ zeb,
        const float* __restrict__ zmw, const float* __restrict__ zmb,
        const float* __restrict__ zsw, const float* __restrict__ zsb,
        float* __restrict__ out) {
    __shared__ __align__(16) float cst[256 * 36];
    __shared__ __align__(16) float a1t[128 * 36];
    __shared__ float ts[32 * 32];
    __shared__ float tv[128];
    __shared__ float eg_s[64], ez_s[64];
    __shared__ float red[256];
    __shared__ float redb[512];
    int tid = threadIdx.x;

    for (int i = tid; i < 32 * 256; i += 256) {
        int w = i >> 8, k = i & 255;
        cst[k * 36 + w] = cs_g[i];
    }
    __syncthreads();

    {   // GEMM1: a1 = relu(cs @ te2w1 + b1)   [32 x 128]
        int wg = tid >> 5, jg = tid & 31;
        int w0 = wg * 4, j0 = jg * 4;
        float acc[4][4] = {};
        for (int k = 0; k < 256; k++) {
            float4 cv4 = *(const float4*)&cst[k * 36 + w0];
            float4 wv4 = *(const float4*)&te2w1[k * 128 + j0];
            float cva[4] = {cv4.x, cv4.y, cv4.z, cv4.w};
            float wva[4] = {wv4.x, wv4.y, wv4.z, wv4.w};
            #pragma unroll
            for (int i = 0; i < 4; i++)
                #pragma unroll
                for (int j = 0; j < 4; j++)
                    acc[i][j] = fmaf(cva[i], wva[j], acc[i][j]);
        }
        #pragma unroll
        for (int jj = 0; jj < 4; jj++) {
            float b = te2b1[j0 + jj];
            #pragma unroll
            for (int i = 0; i < 4; i++)
                a1t[(j0 + jj) * 36 + w0 + i] = fmaxf(acc[i][jj] + b, 0.f);
        }
    }
    __syncthreads();

    {   // GEMM2: ts = a1 @ te2w2 + b2   [32 x 32]
        int wg = tid >> 4, jg = tid & 15;
        int w0 = wg * 2, j0 = jg * 2;
        float acc[2][2] = {};
        for (int k = 0; k < 128; k++) {
            float2 a2 = *(const float2*)&a1t[k * 36 + w0];
            float2 b2v = *(const float2*)&te2w2[k * 32 + j0];
            acc[0][0] = fmaf(a2.x, b2v.x, acc[0][0]);
            acc[0][1] = fmaf(a2.x, b2v.y, acc[0][1]);
            acc[1][0] = fmaf(a2.y, b2v.x, acc[1][0]);
            acc[1][1] = fmaf(a2.y, b2v.y, acc[1][1]);
        }
        #pragma unroll
        for (int i = 0; i < 2; i++)
            #pragma unroll
            for (int j = 0; j < 2; j++)
                ts[(w0 + i) * 32 + (j0 + j)] = acc[i][j] + te2b2[j0 + j];
    }

    // ---- omega partials: 32 w x 8 k-parts over all 256 threads ----
    {
        int w = tid & 31, part = tid >> 5;
        int k0 = part * 32;
        float am = 0.f, as = 0.f;
        #pragma unroll 4
        for (int k = k0; k < k0 + 32; k++) {
            float cv = cst[k * 36 + w];
            am = fmaf(cv, omw[k], am);
            as = fmaf(cv, osw[k], as);
        }
        redb[part * 32 + w] = am;
        redb[256 + part * 32 + w] = as;
    }
    __syncthreads();

    float muo = 0.f, sdo = 1.f;
    if (tid < 32) {
        // omega finish
        float am = 0.f, as = 0.f;
        #pragma unroll
        for (int p = 0; p < 8; p++) {
            am += redb[p * 32 + tid];
            as += redb[256 + p * 32 + tid];
        }
        muo = fmaxf(am + omb[0], 0.f);
        sdo = softplus_f(fmaxf(as + osb[0], 0.f));
        out[tid] = muo;
    } else if (tid < 64) {
        // t stats -> tv
        int t_ = tid - 32;
        float csum = 0.f;
        for (int w2 = 0; w2 < 32; w2++) csum += card[w2];
        float s = 0.f, s2 = 0.f;
        for (int w2 = 0; w2 < 32; w2++) { float v = ts[w2 * 32 + t_]; s += v; s2 += v * v; }
        float m  = s / 32.f;
        float vv = (s2 - s * s / 32.f) / 31.f;
        #pragma unroll
        for (int j = 0; j < 4; j++)
            tv[t_ * 4 + j] = fmaxf(m * t2w[j] + vv * t2w[4 + j] + csum * t2w[8 + j] + t2b[j], 0.f);
    }
    __syncthreads();

    // ---- gamma/zeta hidden layer: 64 j x 4 k-parts over all 256 threads ----
    {
        int j = tid & 63, part = tid >> 6;
        int k0 = part * 32;
        float ag = 0.f, az = 0.f;
        #pragma unroll 4
        for (int k = k0; k < k0 + 32; k++) {
            float t = tv[k];
            ag = fmaf(t, gaw[k * 64 + j], ag);
            az = fmaf(t, zew[k * 64 + j], az);
        }
        redb[part * 64 + j] = ag;
        redb[256 + part * 64 + j] = az;
    }
    __syncthreads();
    if (tid < 64) {
        float ag = gab[tid], az = zeb[tid];
        #pragma unroll
        for (int p = 0; p < 4; p++) {
            ag += redb[p * 64 + tid];
            az += redb[256 + p * 64 + tid];
        }
        eg_s[tid] = fmaxf(ag, 0.f);
        ez_s[tid] = fmaxf(az, 0.f);
    }
    __syncthreads();

    float r = 0.f;
    {
        int j = tid;
        float am = zmb[j], as = zsb[j];
        for (int k = 0; k < 64; k++) {
            float e = ez_s[k];
            am = fmaf(e, zmw[k * 256 + j], am);
            as = fmaf(e, zsw[k * 256 + j], as);
        }
        float mu = fmaxf(am, 0.f);
        float sd = softplus_f(fmaxf(as, 0.f));
        out[37 + j] = mu;
        r += kl_f(mu, sd);
    }
    if (tid < 5) {
        float am = gmb[tid], as = gsb[tid];
        for (int k = 0; k < 64; k++) {
            float e = eg_s[k];
            am = fmaf(e, gmw[k * 5 + tid], am);
            as = fmaf(e, gsw[k * 5 + tid], as);
        }
        float mu = fmaxf(am, 0.f);
        float sd = softplus_f(fmaxf(as, 0.f));
        out[32 + tid] = mu;
        r += kl_f(mu, sd);
    }
    if (tid < 32) r += kl_f(muo, sdo);   // omega KL lives in lanes 0..31
    red[tid] = r;
    __syncthreads();
    for (int s = 128; s > 0; s >>= 1) {
        if (tid < s) red[tid] += red[tid + s];
        __syncthreads();
    }
    if (tid == 0) out[293] = red[0];
}

// ---------------------------------------------------------------------------
extern "C" void kernel_launch(void* const* d_in, const int* in_sizes, int n_in,
                              void* d_out, int out_size, void* d_ws, size_t ws_size,
                              hipStream_t stream) {
    const float* x    = (const float*)d_in[0];
    const float* y    = (const float*)d_in[1];
    const float* w1   = (const float*)d_in[2];
    const float* b1   = (const float*)d_in[3];
    const float* w2   = (const float*)d_in[4];
    const float* b2   = (const float*)d_in[5];
    const float* encw = (const float*)d_in[6];
    const float* encb = (const float*)d_in[7];
    const float* t1w  = (const float*)d_in[8];
    const float* t1b  = (const float*)d_in[9];
    const float* te2w1 = (const float*)d_in[10];
    const float* te2b1 = (const float*)d_in[11];
    const float* te2w2 = (const float*)d_in[12];
    const float* te2b2 = (const float*)d_in[13];
    const float* t2w  = (const float*)d_in[14];
    const float* t2b  = (const float*)d_in[15];
    const float* omw  = (const float*)d_in[16];
    const float* omb  = (const float*)d_in[17];
    const float* osw  = (const float*)d_in[18];
    const float* osb  = (const float*)d_in[19];
    const float* gaw  = (const float*)d_in[20];
    const float* gab  = (const float*)d_in[21];
    const float* gmw  = (const float*)d_in[22];
    const float* gmb  = (const float*)d_in[23];
    const float* gsw  = (const float*)d_in[24];
    const float* gsb  = (const float*)d_in[25];
    const float* zew  = (const float*)d_in[26];
    const float* zeb  = (const float*)d_in[27];
    const float* zmw  = (const float*)d_in[28];
    const float* zmb  = (const float*)d_in[29];
    const float* zsw  = (const float*)d_in[30];
    const float* zsb  = (const float*)d_in[31];
    float* out = (float*)d_out;

    float* p2   = (float*)d_ws;                       // [2048][3610]
    float* H    = p2 + (size_t)NTOT * FLAT;           // [2048][64]
    int*   lbl  = (int*)(H + NTOT * 64);              // [2048] (unused, layout kept)
    float* cs   = (float*)(lbl + NTOT);               // [32][256]
    float* card = cs + 32 * 256;                      // [32]

    hipMemsetAsync(H, 0, NTOT * 64 * sizeof(float), stream);
    hipLaunchKernelGGL(k_conv, dim3(NTOT * 4), dim3(256), 0, stream, x, w1, b1, w2, b2, p2);
    hipLaunchKernelGGL(k_enc, dim3(32 * KSPLIT), dim3(256), 0, stream, p2, encw, H);
    hipLaunchKernelGGL(k_stats, dim3(32), dim3(1024), 0, stream, H, encb, y, t1w, t1b, cs, card);
    hipLaunchKernelGGL(k_head, dim3(1), dim3(256), 0, stream, cs, card,
                       te2w1, te2b1, te2w2, te2b2, t2w, t2b,
                       omw, omb, osw, osb, gaw, gab, gmw, gmb, gsw, gsb,
                       zew, zeb, zmw, zmb, zsw, zsb, out);
}